// Round 11
// baseline (779.858 us; speedup 1.0000x reference)
//
#include <hip/hip_runtime.h>
#include <hip/hip_bf16.h>
#include <math.h>

#define V 65536
#define G 2048
#define NPG 32
#define DEG 4
#define NE (V*DEG)
#define H 200
#define NODE_IN 74
#define EDGE_IN 12
#define NL 5

#define KP 224      // GEMM K padded (7 x 32)
#define NP 208      // feature dim padded (13 x 16)
#define AGS 209     // agg LDS row stride in u32 (209%32=17 -> spread banks on b128)
#define EK 32       // edge-mfma K
#define HS 200      // h_s row stride (floats)

typedef __attribute__((ext_vector_type(8))) short short8;
typedef __attribute__((ext_vector_type(4))) float floatx4;

__device__ __forceinline__ float sigmoidf_(float x) { return 1.f / (1.f + __expf(-x)); }

__device__ __forceinline__ unsigned f2bf_bits(float f) {
    unsigned u = __float_as_uint(f);
    return (u + 0x7fffu + ((u >> 16) & 1u)) >> 16;  // RNE
}
__device__ __forceinline__ float bf2f(unsigned bits) { return __uint_as_float(bits << 16); }
__device__ __forceinline__ unsigned lo_bits(float f, unsigned hb) {
    return f2bf_bits(f - bf2f(hb));
}

// ---------------- node embedding (fp32) ----------------
__global__ __launch_bounds__(256) void k_node_embed(const float* __restrict__ nf,
                                                    const float* __restrict__ W,
                                                    const float* __restrict__ b,
                                                    float* __restrict__ h) {
    __shared__ float fs[16][NODE_IN];
    const int tid = threadIdx.x;
    const int base = blockIdx.x * 16;
    for (int p = tid; p < 16 * NODE_IN; p += 256) {
        int n = p / NODE_IN, i = p - n * NODE_IN;
        fs[n][i] = nf[(base + n) * NODE_IN + i];
    }
    __syncthreads();
    const int j = tid;
    if (j < H) {
        float acc[16];
#pragma unroll
        for (int n = 0; n < 16; n++) acc[n] = 0.f;
        for (int i = 0; i < NODE_IN; i++) {
            float w = W[i * H + j];
#pragma unroll
            for (int n = 0; n < 16; n++) acc[n] = fmaf(fs[n][i], w, acc[n]);
        }
        float bj = b[j];
        for (int n = 0; n < 16; n++) h[(base + n) * H + j] = acc[n] + bj;
    }
}

// ---------------- merged small preps (gnn_W planes + edge_W planes) ----------------
#define SEG_W (NL * NP * KP)
#define SEG_EW NP
__global__ __launch_bounds__(256) void k_prep_all(const float* __restrict__ gnnW,
                                                  const float* __restrict__ eW,
                                                  const float* __restrict__ eb,
                                                  unsigned short* __restrict__ WtHi,
                                                  unsigned short* __restrict__ WtLo,
                                                  unsigned short* __restrict__ eWp) {
    int idx = blockIdx.x * 256 + threadIdx.x;
    if (idx < SEG_W) {
        int l = idx / (NP * KP);
        int rem = idx - l * (NP * KP);
        int n = rem / KP;
        int k = rem - n * KP;
        float w = (n < H && k < H) ? gnnW[l * H * H + k * H + n] : 0.f;
        unsigned hb = f2bf_bits(w);
        WtHi[idx] = (unsigned short)hb;
        WtLo[idx] = (unsigned short)lo_bits(w, hb);
        return;
    }
    idx -= SEG_W;
    if (idx < SEG_EW) {
        int t = idx;
        unsigned short row[64];
        for (int i = 0; i < 64; i++) row[i] = 0;
        if (t < H) {
            for (int k = 0; k < EDGE_IN; k++) {
                float w = eW[k * H + t];
                unsigned hb = f2bf_bits(w);
                row[k] = (unsigned short)hb;
                row[12 + k] = (unsigned short)hb;
                row[32 + k] = (unsigned short)lo_bits(w, hb);
            }
            float e = eb[t];
            unsigned ebh = f2bf_bits(e);
            row[24] = (unsigned short)ebh;
            row[25] = (unsigned short)lo_bits(e, ebh);
        }
        for (int i = 0; i < 64; i++) eWp[t * 64 + i] = row[i];
    }
}

// ---------------- prep: ef -> edge A-plane [NE][EK] ----------------
__global__ __launch_bounds__(256) void k_prep_ef(const float* __restrict__ ef,
                                                 unsigned short* __restrict__ Aedge) {
    __shared__ float efs[256 * EDGE_IN];
    const int tid = threadIdx.x, blk = blockIdx.x;
    const float4* gs = (const float4*)(ef + (size_t)blk * 256 * EDGE_IN);
    float4* ds = (float4*)efs;
    for (int p = tid; p < 256 * EDGE_IN / 4; p += 256) ds[p] = gs[p];
    __syncthreads();
    unsigned hb[EDGE_IN], lb[EDGE_IN];
    for (int k = 0; k < EDGE_IN; k++) {
        float v = efs[tid * EDGE_IN + k];
        hb[k] = f2bf_bits(v);
        lb[k] = lo_bits(v, hb[k]);
    }
    unsigned w[16];
    for (int i = 0; i < 6; i++) w[i] = hb[2 * i] | (hb[2 * i + 1] << 16);
    for (int i = 0; i < 6; i++) w[6 + i] = lb[2 * i] | (lb[2 * i + 1] << 16);
    w[12] = 0x3F803F80u;
    w[13] = 0u; w[14] = 0u; w[15] = 0u;
    uint4* dst = (uint4*)(Aedge + ((size_t)blk * 256 + tid) * EK);
    dst[0] = make_uint4(w[0], w[1], w[2], w[3]);
    dst[1] = make_uint4(w[4], w[5], w[6], w[7]);
    dst[2] = make_uint4(w[8], w[9], w[10], w[11]);
    dst[3] = make_uint4(w[12], w[13], w[14], w[15]);
}

// ---------------- MEGA (R9 bit-identical): 5 GNN layers + gf ----------------
__global__ __launch_bounds__(256, 3) void k_mega(float* __restrict__ h,
                                                 const unsigned short* __restrict__ Aedge,
                                                 const unsigned short* __restrict__ eWp,
                                                 const int* __restrict__ src,
                                                 const unsigned short* __restrict__ WtHi,
                                                 const unsigned short* __restrict__ WtLo,
                                                 const float* __restrict__ gnn_b,
                                                 float* __restrict__ gf_out) {
    __shared__ alignas(16) float h_s[NPG * HS];
    __shared__ alignas(16) unsigned int agg[NPG * AGS];
    __shared__ alignas(16) unsigned int zpad[8];
    __shared__ unsigned char src_s[NPG * DEG];
    const int g = blockIdx.x, tid = threadIdx.x;
    const int nbase = g * NPG, ebase = g * NPG * DEG;

    const int wave = tid >> 6, lane = tid & 63;
    const int l15 = lane & 15, quad = lane >> 4;
    const int ntcnt = (wave == 0) ? 4 : 3;

    short8 af[8];
    {
        const unsigned short* abase = Aedge + (size_t)ebase * EK;
#pragma unroll
        for (int mt = 0; mt < 8; mt++)
            af[mt] = *(const short8*)&abase[(16 * mt + l15) * EK + quad * 8];
    }
    if (tid < NPG * DEG) src_s[tid] = (unsigned char)(src[ebase + tid] - nbase);
    if (tid < 8) zpad[tid] = 0u;
    {
        const float4* hsrc = (const float4*)(h + (size_t)nbase * H);
        float4* hdst = (float4*)h_s;
        for (int p = tid; p < NPG * H / 4; p += 256) hdst[p] = hsrc[p];
    }
    __syncthreads();

    for (int l = 0; l < NL; l++) {
        for (int i = 0; i < ntcnt; i++) {
            int nt = wave + 4 * i, jj = nt * 16 + l15;
            short8 b1 = *(const short8*)&eWp[(size_t)jj * 64 + quad * 8];
            short8 b2 = *(const short8*)&eWp[(size_t)jj * 64 + 32 + quad * 8];
            int jc = jj < H ? jj : H - 1;
            float mh[8][4];
#pragma unroll
            for (int mt = 0; mt < 8; mt++) {
                const int node = 4 * mt + quad;
#pragma unroll
                for (int e = 0; e < 4; e++)
                    mh[mt][e] = h_s[src_s[node * 4 + e] * HS + jc];
            }
#pragma unroll
            for (int mt = 0; mt < 8; mt++) {
                floatx4 z = (floatx4){0.f, 0.f, 0.f, 0.f};
                z = __builtin_amdgcn_mfma_f32_16x16x32_bf16(af[mt], b1, z, 0, 0, 0);
                z = __builtin_amdgcn_mfma_f32_16x16x32_bf16(af[mt], b2, z, 0, 0, 0);
                const int node = 4 * mt + quad;
                float m0 = z[0] + mh[mt][0];
                float m1 = z[1] + mh[mt][1];
                float m2 = z[2] + mh[mt][2];
                float m3 = z[3] + mh[mt][3];
                float mx = fmaxf(fmaxf(m0, m1), fmaxf(m2, m3));
                float e0 = __expf(m0 - mx), e1 = __expf(m1 - mx);
                float e2 = __expf(m2 - mx), e3 = __expf(m3 - mx);
                float den = e0 + e1 + e2 + e3;
                float num = fmaf(m0, e0, fmaf(m1, e1, fmaf(m2, e2, m3 * e3)));
                float a = __fdividef(num, den);
                if (jj >= H) a = 0.f;
                unsigned hbb = f2bf_bits(a);
                unsigned lbb = lo_bits(a, hbb);
                unsigned short* rowp = (unsigned short*)(agg + node * AGS);
                int c = jj >> 3, o = jj & 7;
                rowp[c * 16 + o] = (unsigned short)hbb;
                rowp[c * 16 + 8 + o] = (unsigned short)lbb;
            }
        }
        __syncthreads();

        floatx4 acc2[2][4];
#pragma unroll
        for (int mt = 0; mt < 2; mt++)
#pragma unroll
            for (int i = 0; i < 4; i++) acc2[mt][i] = (floatx4){0.f, 0.f, 0.f, 0.f};

        const unsigned short* WH = WtHi + (size_t)l * NP * KP;
        const unsigned short* WL = WtLo + (size_t)l * NP * KP;
        for (int ks = 0; ks < KP / 32; ks++) {
            const int c = 4 * ks + quad;
            short8 ah[2], al[2];
#pragma unroll
            for (int mt = 0; mt < 2; mt++) {
                const unsigned int* ap = (c < 26) ? &agg[(16 * mt + l15) * AGS + c * 8]
                                                  : (const unsigned int*)zpad;
                ah[mt] = *(const short8*)ap;
                al[mt] = *(const short8*)(ap + 4);
            }
#pragma unroll 4
            for (int i = 0; i < ntcnt; i++) {
                int nt = wave + 4 * i;
                size_t boff = (size_t)(16 * nt + l15) * KP + ks * 32 + quad * 8;
                short8 vbh = *(const short8*)&WH[boff];
                short8 vbl = *(const short8*)&WL[boff];
#pragma unroll
                for (int mt = 0; mt < 2; mt++) {
                    acc2[mt][i] = __builtin_amdgcn_mfma_f32_16x16x32_bf16(ah[mt], vbh, acc2[mt][i], 0, 0, 0);
                    acc2[mt][i] = __builtin_amdgcn_mfma_f32_16x16x32_bf16(al[mt], vbh, acc2[mt][i], 0, 0, 0);
                    acc2[mt][i] = __builtin_amdgcn_mfma_f32_16x16x32_bf16(ah[mt], vbl, acc2[mt][i], 0, 0, 0);
                }
            }
        }
        for (int i = 0; i < ntcnt; i++) {
            int nt = wave + 4 * i, jj = nt * 16 + l15;
            if (jj < H) {
                float bj = gnn_b[l * H + jj];
#pragma unroll
                for (int mt = 0; mt < 2; mt++) {
#pragma unroll
                    for (int r = 0; r < 4; r++) {
                        float v = acc2[mt][i][r] + bj;
                        v = v > 0.f ? v : 0.f;
                        h_s[(16 * mt + quad * 4 + r) * HS + jj] += v;
                    }
                }
            }
        }
        __syncthreads();
    }

    {
        float4* dst = (float4*)(h + (size_t)nbase * H);
        const float4* srcp = (const float4*)h_s;
        for (int p = tid; p < NPG * H / 4; p += 256) dst[p] = srcp[p];
    }
    if (tid < H) {
        float s = 0.f;
        for (int n = 0; n < NPG; n++) s += h_s[n * HS + tid];
        gf_out[g * H + tid] = s;
    }
}

// ---------------- readout attention: ends at wh (no weight GEMM) ----------------
__global__ __launch_bounds__(256) void k_attn(const float* __restrict__ h,
                                              const float* __restrict__ gf,
                                              const float* __restrict__ lgW,
                                              const float* __restrict__ lgb,
                                              float* __restrict__ wh_out) {
    __shared__ float h_s[NPG][H];
    __shared__ float gf_s[H];
    __shared__ float z_s[NPG];
    __shared__ float a_s[NPG];
    __shared__ float den_s;
    const int g = blockIdx.x, tid = threadIdx.x;
    const int lane = tid & 63;

    for (int p = tid; p < NPG * H; p += 256) h_s[0][p] = h[g * NPG * H + p];
    if (tid < H) gf_s[tid] = gf[g * H + tid];
    __syncthreads();

    {
        const int n = tid >> 3, l = tid & 7;
        float p = 0.f;
        for (int jj = l; jj < H; jj += 8) {
            p = fmaf(h_s[n][jj], lgW[H + jj], p);
            p = fmaf(fmaxf(gf_s[jj], 0.f), lgW[jj], p);
        }
        p += __shfl_xor(p, 1);
        p += __shfl_xor(p, 2);
        p += __shfl_xor(p, 4);
        if (l == 0) {
            float z = p + lgb[0];
            z_s[n] = z > 0.f ? z : 0.01f * z;
        }
    }
    __syncthreads();

    if (tid < 64) {
        float z = (lane < NPG) ? z_s[lane] : -1e30f;
        float m = z;
        m = fmaxf(m, __shfl_xor(m, 1));
        m = fmaxf(m, __shfl_xor(m, 2));
        m = fmaxf(m, __shfl_xor(m, 4));
        m = fmaxf(m, __shfl_xor(m, 8));
        m = fmaxf(m, __shfl_xor(m, 16));
        float e = (lane < NPG) ? __expf(z - m) : 0.f;
        float d = e;
        d += __shfl_xor(d, 1);
        d += __shfl_xor(d, 2);
        d += __shfl_xor(d, 4);
        d += __shfl_xor(d, 8);
        d += __shfl_xor(d, 16);
        if (lane < NPG) a_s[lane] = e;
        if (lane == 0) den_s = d;
    }
    __syncthreads();

    if (tid < H) {
        float s = 0.f;
        for (int n = 0; n < NPG; n++) s = fmaf(a_s[n], h_s[n][tid], s);
        wh_out[g * H + tid] = s / den_s;
    }
}

// ---------------- ctx projection: 16 graphs/block, weight reuse ----------------
#define PGB 16
__global__ __launch_bounds__(256) void k_proj(const float* __restrict__ wh,
                                              const float* __restrict__ prW,  // [H][H] original layout
                                              const float* __restrict__ prb,
                                              float* __restrict__ ctx) {
    __shared__ float wh_s[PGB][H];  // 12.8 KB
    const int gbase = blockIdx.x * PGB, tid = threadIdx.x;
    for (int p = tid; p < PGB * H; p += 256) wh_s[0][p] = wh[(size_t)gbase * H + p];
    __syncthreads();
    const int j = tid;
    if (j < H) {
        float acc[PGB];
#pragma unroll
        for (int q = 0; q < PGB; q++) acc[q] = 0.f;
        for (int i = 0; i < H; i++) {
            float w = prW[i * H + j];  // coalesced across j; reused by 16 graphs
#pragma unroll
            for (int q = 0; q < PGB; q++) acc[q] = fmaf(wh_s[q][i], w, acc[q]);
        }
        float bj = prb[j];
        for (int q = 0; q < PGB; q++) {
            float s = acc[q] + bj;
            ctx[(size_t)(gbase + q) * H + j] = s > 0.f ? s : __expf(s) - 1.f;  // elu
        }
    }
}

// ---------------- GRU cell (R10 version): 512 threads ----------------
#define GPB 8
#define GP 9
__global__ __launch_bounds__(512) void k_gru(const float* __restrict__ ctx,
                                             const float* __restrict__ gf,
                                             const float* __restrict__ Wih,
                                             const float* __restrict__ Whh,
                                             const float* __restrict__ bih,
                                             const float* __restrict__ bhh,
                                             float* __restrict__ gf_out) {
    __shared__ float ctx_s[GPB][H];
    __shared__ float gfs[GPB][H];
    __shared__ float gi_s[3 * H][GP];
    __shared__ float gh_s[3 * H][GP];
    const int gbase = blockIdx.x * GPB, tid = threadIdx.x;

    for (int p = tid; p < GPB * H; p += 512) {
        ctx_s[0][p] = ctx[gbase * H + p];
        gfs[0][p] = gf[gbase * H + p];
    }
    __syncthreads();

    for (int k = tid; k < 3 * H; k += 512) {
        float ai[GPB], ah[GPB];
        float bi = bih[k], bh = bhh[k];
#pragma unroll
        for (int q = 0; q < GPB; q++) { ai[q] = bi; ah[q] = bh; }
        const float4* wi4 = (const float4*)(Wih + (size_t)k * H);
        const float4* wh4 = (const float4*)(Whh + (size_t)k * H);
        for (int j4 = 0; j4 < H / 4; j4++) {
            float4 wi = wi4[j4];
            float4 wh = wh4[j4];
            int jj = j4 * 4;
#pragma unroll
            for (int q = 0; q < GPB; q++) {
                ai[q] = fmaf(ctx_s[q][jj + 0], wi.x, ai[q]);
                ai[q] = fmaf(ctx_s[q][jj + 1], wi.y, ai[q]);
                ai[q] = fmaf(ctx_s[q][jj + 2], wi.z, ai[q]);
                ai[q] = fmaf(ctx_s[q][jj + 3], wi.w, ai[q]);
                ah[q] = fmaf(gfs[q][jj + 0], wh.x, ah[q]);
                ah[q] = fmaf(gfs[q][jj + 1], wh.y, ah[q]);
                ah[q] = fmaf(gfs[q][jj + 2], wh.z, ah[q]);
                ah[q] = fmaf(gfs[q][jj + 3], wh.w, ah[q]);
            }
        }
#pragma unroll
        for (int q = 0; q < GPB; q++) { gi_s[k][q] = ai[q]; gh_s[k][q] = ah[q]; }
    }
    __syncthreads();

    for (int p = tid; p < GPB * H; p += 512) {
        int q = p / H, jj = p - q * H;
        float r = sigmoidf_(gi_s[jj][q] + gh_s[jj][q]);
        float u = sigmoidf_(gi_s[H + jj][q] + gh_s[H + jj][q]);
        float nn = tanhf(gi_s[2 * H + jj][q] + r * gh_s[2 * H + jj][q]);
        gf_out[(gbase + q) * H + jj] = (1.f - u) * nn + u * gfs[q][jj];
    }
}

extern "C" void kernel_launch(void* const* d_in, const int* in_sizes, int n_in,
                              void* d_out, int out_size, void* d_ws, size_t ws_size,
                              hipStream_t stream) {
    const float* node_feat = (const float*)d_in[0];
    const float* edge_feat = (const float*)d_in[1];
    const int* src = (const int*)d_in[2];
    const float* node_W = (const float*)d_in[5];
    const float* node_b = (const float*)d_in[6];
    const float* edge_W = (const float*)d_in[7];
    const float* edge_b = (const float*)d_in[8];
    const float* gnn_W = (const float*)d_in[9];
    const float* gnn_b = (const float*)d_in[10];
    const float* lg_W = (const float*)d_in[11];
    const float* lg_b = (const float*)d_in[12];
    const float* pr_W = (const float*)d_in[13];
    const float* pr_b = (const float*)d_in[14];
    const float* W_ih = (const float*)d_in[15];
    const float* W_hh = (const float*)d_in[16];
    const float* b_ih = (const float*)d_in[17];
    const float* b_hh = (const float*)d_in[18];
    float* out = (float*)d_out;

    char* ws = (char*)d_ws;
    size_t off = 0;
    auto alloc = [&](size_t bytes) { void* p = ws + off; off += (bytes + 4095) & ~(size_t)4095; return p; };
    float* h = (float*)alloc((size_t)V * H * 4);
    unsigned short* Aedge = (unsigned short*)alloc((size_t)NE * EK * 2);
    unsigned short* WtHi = (unsigned short*)alloc((size_t)NL * NP * KP * 2);
    unsigned short* WtLo = (unsigned short*)alloc((size_t)NL * NP * KP * 2);
    unsigned short* eWp = (unsigned short*)alloc((size_t)NP * 64 * 2);
    float* gf_ws = (float*)alloc((size_t)G * H * 4);
    float* wh_ws = (float*)alloc((size_t)G * H * 4);
    float* ctx_ws = (float*)alloc((size_t)G * H * 4);

    {
        int total = SEG_W + SEG_EW;
        k_prep_all<<<(total + 255) / 256, 256, 0, stream>>>(gnn_W, edge_W, edge_b,
                                                            WtHi, WtLo, eWp);
    }
    k_prep_ef<<<NE / 256, 256, 0, stream>>>(edge_feat, Aedge);
    k_node_embed<<<V / 16, 256, 0, stream>>>(node_feat, node_W, node_b, h);

    k_mega<<<G, 256, 0, stream>>>(h, Aedge, eWp, src, WtHi, WtLo, gnn_b, gf_ws);

    for (int t = 0; t < 2; t++) {
        k_attn<<<G, 256, 0, stream>>>(h, gf_ws, lg_W + (size_t)t * 2 * H, lg_b + t, wh_ws);
        k_proj<<<G / PGB, 256, 0, stream>>>(wh_ws, pr_W + (size_t)t * H * H,
                                            pr_b + (size_t)t * H, ctx_ws);
        float* gout = (t == 1) ? out : gf_ws;
        k_gru<<<G / GPB, 512, 0, stream>>>(ctx_ws, gf_ws, W_ih + (size_t)t * 3 * H * H,
                                           W_hh + (size_t)t * 3 * H * H, b_ih + (size_t)t * 3 * H,
                                           b_hh + (size_t)t * 3 * H, gout);
    }
}

// Round 12
// 739.431 us; speedup vs baseline: 1.0547x; 1.0547x over previous
//
#include <hip/hip_runtime.h>
#include <hip/hip_bf16.h>
#include <math.h>

#define V 65536
#define G 2048
#define NPG 32
#define DEG 4
#define NE (V*DEG)
#define H 200
#define NODE_IN 74
#define EDGE_IN 12
#define NL 5

#define KP 224      // GEMM K padded (7 x 32)
#define NP 208      // feature dim padded (13 x 16)
#define AGS 209     // agg LDS row stride in u32 (209%32=17 -> spread banks on b128)
#define EK 32       // edge-mfma K
#define HS 200      // h_s row stride (floats)

typedef __attribute__((ext_vector_type(8))) short short8;
typedef __attribute__((ext_vector_type(4))) float floatx4;

__device__ __forceinline__ float sigmoidf_(float x) { return 1.f / (1.f + __expf(-x)); }

__device__ __forceinline__ unsigned f2bf_bits(float f) {
    unsigned u = __float_as_uint(f);
    return (u + 0x7fffu + ((u >> 16) & 1u)) >> 16;  // RNE
}
__device__ __forceinline__ float bf2f(unsigned bits) { return __uint_as_float(bits << 16); }
__device__ __forceinline__ unsigned lo_bits(float f, unsigned hb) {
    return f2bf_bits(f - bf2f(hb));
}

// ---------------- node embedding (fp32) ----------------
__global__ __launch_bounds__(256) void k_node_embed(const float* __restrict__ nf,
                                                    const float* __restrict__ W,
                                                    const float* __restrict__ b,
                                                    float* __restrict__ h) {
    __shared__ float fs[16][NODE_IN];
    const int tid = threadIdx.x;
    const int base = blockIdx.x * 16;
    for (int p = tid; p < 16 * NODE_IN; p += 256) {
        int n = p / NODE_IN, i = p - n * NODE_IN;
        fs[n][i] = nf[(base + n) * NODE_IN + i];
    }
    __syncthreads();
    const int j = tid;
    if (j < H) {
        float acc[16];
#pragma unroll
        for (int n = 0; n < 16; n++) acc[n] = 0.f;
        for (int i = 0; i < NODE_IN; i++) {
            float w = W[i * H + j];
#pragma unroll
            for (int n = 0; n < 16; n++) acc[n] = fmaf(fs[n][i], w, acc[n]);
        }
        float bj = b[j];
        for (int n = 0; n < 16; n++) h[(base + n) * H + j] = acc[n] + bj;
    }
}

// ---------------- fused prep: blocks 0..EFB-1 = edge A-planes; rest = W/eW segments ----------------
#define EFB (NE / 256)               // 1024 edge-plane blocks
#define SEG_W (NL * NP * KP)
#define SEG_EW NP
__global__ __launch_bounds__(256) void k_prep(const float* __restrict__ ef,
                                              const float* __restrict__ gnnW,
                                              const float* __restrict__ eW,
                                              const float* __restrict__ eb,
                                              unsigned short* __restrict__ Aedge,
                                              unsigned short* __restrict__ WtHi,
                                              unsigned short* __restrict__ WtLo,
                                              unsigned short* __restrict__ eWp) {
    __shared__ float efs[256 * EDGE_IN];
    const int tid = threadIdx.x, blk = blockIdx.x;
    if (blk < EFB) {
        const float4* gs = (const float4*)(ef + (size_t)blk * 256 * EDGE_IN);
        float4* ds = (float4*)efs;
        for (int p = tid; p < 256 * EDGE_IN / 4; p += 256) ds[p] = gs[p];
        __syncthreads();
        unsigned hb[EDGE_IN], lb[EDGE_IN];
        for (int k = 0; k < EDGE_IN; k++) {
            float v = efs[tid * EDGE_IN + k];
            hb[k] = f2bf_bits(v);
            lb[k] = lo_bits(v, hb[k]);
        }
        unsigned w[16];
        for (int i = 0; i < 6; i++) w[i] = hb[2 * i] | (hb[2 * i + 1] << 16);
        for (int i = 0; i < 6; i++) w[6 + i] = lb[2 * i] | (lb[2 * i + 1] << 16);
        w[12] = 0x3F803F80u;
        w[13] = 0u; w[14] = 0u; w[15] = 0u;
        uint4* dst = (uint4*)(Aedge + ((size_t)blk * 256 + tid) * EK);
        dst[0] = make_uint4(w[0], w[1], w[2], w[3]);
        dst[1] = make_uint4(w[4], w[5], w[6], w[7]);
        dst[2] = make_uint4(w[8], w[9], w[10], w[11]);
        dst[3] = make_uint4(w[12], w[13], w[14], w[15]);
        return;
    }
    int idx = (blk - EFB) * 256 + tid;
    if (idx < SEG_W) {
        int l = idx / (NP * KP);
        int rem = idx - l * (NP * KP);
        int n = rem / KP;
        int k = rem - n * KP;
        float w = (n < H && k < H) ? gnnW[l * H * H + k * H + n] : 0.f;
        unsigned hb = f2bf_bits(w);
        WtHi[idx] = (unsigned short)hb;
        WtLo[idx] = (unsigned short)lo_bits(w, hb);
        return;
    }
    idx -= SEG_W;
    if (idx < SEG_EW) {
        int t = idx;
        unsigned short row[64];
        for (int i = 0; i < 64; i++) row[i] = 0;
        if (t < H) {
            for (int k = 0; k < EDGE_IN; k++) {
                float w = eW[k * H + t];
                unsigned hb = f2bf_bits(w);
                row[k] = (unsigned short)hb;
                row[12 + k] = (unsigned short)hb;
                row[32 + k] = (unsigned short)lo_bits(w, hb);
            }
            float e = eb[t];
            unsigned ebh = f2bf_bits(e);
            row[24] = (unsigned short)ebh;
            row[25] = (unsigned short)lo_bits(e, ebh);
        }
        for (int i = 0; i < 64; i++) eWp[t * 64 + i] = row[i];
    }
}

// ---------------- MEGA (R9 bit-identical): 5 GNN layers + gf ----------------
__global__ __launch_bounds__(256, 3) void k_mega(float* __restrict__ h,
                                                 const unsigned short* __restrict__ Aedge,
                                                 const unsigned short* __restrict__ eWp,
                                                 const int* __restrict__ src,
                                                 const unsigned short* __restrict__ WtHi,
                                                 const unsigned short* __restrict__ WtLo,
                                                 const float* __restrict__ gnn_b,
                                                 float* __restrict__ gf_out) {
    __shared__ alignas(16) float h_s[NPG * HS];
    __shared__ alignas(16) unsigned int agg[NPG * AGS];
    __shared__ alignas(16) unsigned int zpad[8];
    __shared__ unsigned char src_s[NPG * DEG];
    const int g = blockIdx.x, tid = threadIdx.x;
    const int nbase = g * NPG, ebase = g * NPG * DEG;

    const int wave = tid >> 6, lane = tid & 63;
    const int l15 = lane & 15, quad = lane >> 4;
    const int ntcnt = (wave == 0) ? 4 : 3;

    short8 af[8];
    {
        const unsigned short* abase = Aedge + (size_t)ebase * EK;
#pragma unroll
        for (int mt = 0; mt < 8; mt++)
            af[mt] = *(const short8*)&abase[(16 * mt + l15) * EK + quad * 8];
    }
    if (tid < NPG * DEG) src_s[tid] = (unsigned char)(src[ebase + tid] - nbase);
    if (tid < 8) zpad[tid] = 0u;
    {
        const float4* hsrc = (const float4*)(h + (size_t)nbase * H);
        float4* hdst = (float4*)h_s;
        for (int p = tid; p < NPG * H / 4; p += 256) hdst[p] = hsrc[p];
    }
    __syncthreads();

    for (int l = 0; l < NL; l++) {
        for (int i = 0; i < ntcnt; i++) {
            int nt = wave + 4 * i, jj = nt * 16 + l15;
            short8 b1 = *(const short8*)&eWp[(size_t)jj * 64 + quad * 8];
            short8 b2 = *(const short8*)&eWp[(size_t)jj * 64 + 32 + quad * 8];
            int jc = jj < H ? jj : H - 1;
            float mh[8][4];
#pragma unroll
            for (int mt = 0; mt < 8; mt++) {
                const int node = 4 * mt + quad;
#pragma unroll
                for (int e = 0; e < 4; e++)
                    mh[mt][e] = h_s[src_s[node * 4 + e] * HS + jc];
            }
#pragma unroll
            for (int mt = 0; mt < 8; mt++) {
                floatx4 z = (floatx4){0.f, 0.f, 0.f, 0.f};
                z = __builtin_amdgcn_mfma_f32_16x16x32_bf16(af[mt], b1, z, 0, 0, 0);
                z = __builtin_amdgcn_mfma_f32_16x16x32_bf16(af[mt], b2, z, 0, 0, 0);
                const int node = 4 * mt + quad;
                float m0 = z[0] + mh[mt][0];
                float m1 = z[1] + mh[mt][1];
                float m2 = z[2] + mh[mt][2];
                float m3 = z[3] + mh[mt][3];
                float mx = fmaxf(fmaxf(m0, m1), fmaxf(m2, m3));
                float e0 = __expf(m0 - mx), e1 = __expf(m1 - mx);
                float e2 = __expf(m2 - mx), e3 = __expf(m3 - mx);
                float den = e0 + e1 + e2 + e3;
                float num = fmaf(m0, e0, fmaf(m1, e1, fmaf(m2, e2, m3 * e3)));
                float a = __fdividef(num, den);
                if (jj >= H) a = 0.f;
                unsigned hbb = f2bf_bits(a);
                unsigned lbb = lo_bits(a, hbb);
                unsigned short* rowp = (unsigned short*)(agg + node * AGS);
                int c = jj >> 3, o = jj & 7;
                rowp[c * 16 + o] = (unsigned short)hbb;
                rowp[c * 16 + 8 + o] = (unsigned short)lbb;
            }
        }
        __syncthreads();

        floatx4 acc2[2][4];
#pragma unroll
        for (int mt = 0; mt < 2; mt++)
#pragma unroll
            for (int i = 0; i < 4; i++) acc2[mt][i] = (floatx4){0.f, 0.f, 0.f, 0.f};

        const unsigned short* WH = WtHi + (size_t)l * NP * KP;
        const unsigned short* WL = WtLo + (size_t)l * NP * KP;
        for (int ks = 0; ks < KP / 32; ks++) {
            const int c = 4 * ks + quad;
            short8 ah[2], al[2];
#pragma unroll
            for (int mt = 0; mt < 2; mt++) {
                const unsigned int* ap = (c < 26) ? &agg[(16 * mt + l15) * AGS + c * 8]
                                                  : (const unsigned int*)zpad;
                ah[mt] = *(const short8*)ap;
                al[mt] = *(const short8*)(ap + 4);
            }
#pragma unroll 4
            for (int i = 0; i < ntcnt; i++) {
                int nt = wave + 4 * i;
                size_t boff = (size_t)(16 * nt + l15) * KP + ks * 32 + quad * 8;
                short8 vbh = *(const short8*)&WH[boff];
                short8 vbl = *(const short8*)&WL[boff];
#pragma unroll
                for (int mt = 0; mt < 2; mt++) {
                    acc2[mt][i] = __builtin_amdgcn_mfma_f32_16x16x32_bf16(ah[mt], vbh, acc2[mt][i], 0, 0, 0);
                    acc2[mt][i] = __builtin_amdgcn_mfma_f32_16x16x32_bf16(al[mt], vbh, acc2[mt][i], 0, 0, 0);
                    acc2[mt][i] = __builtin_amdgcn_mfma_f32_16x16x32_bf16(ah[mt], vbl, acc2[mt][i], 0, 0, 0);
                }
            }
        }
        for (int i = 0; i < ntcnt; i++) {
            int nt = wave + 4 * i, jj = nt * 16 + l15;
            if (jj < H) {
                float bj = gnn_b[l * H + jj];
#pragma unroll
                for (int mt = 0; mt < 2; mt++) {
#pragma unroll
                    for (int r = 0; r < 4; r++) {
                        float v = acc2[mt][i][r] + bj;
                        v = v > 0.f ? v : 0.f;
                        h_s[(16 * mt + quad * 4 + r) * HS + jj] += v;
                    }
                }
            }
        }
        __syncthreads();
    }

    {
        float4* dst = (float4*)(h + (size_t)nbase * H);
        const float4* srcp = (const float4*)h_s;
        for (int p = tid; p < NPG * H / 4; p += 256) dst[p] = srcp[p];
    }
    if (tid < H) {
        float s = 0.f;
        for (int n = 0; n < NPG; n++) s += h_s[n * HS + tid];
        gf_out[g * H + tid] = s;
    }
}

// ---------------- readout attention (R11 version): ends at wh ----------------
__global__ __launch_bounds__(256) void k_attn(const float* __restrict__ h,
                                              const float* __restrict__ gf,
                                              const float* __restrict__ lgW,
                                              const float* __restrict__ lgb,
                                              float* __restrict__ wh_out) {
    __shared__ float h_s[NPG][H];
    __shared__ float gf_s[H];
    __shared__ float z_s[NPG];
    __shared__ float a_s[NPG];
    __shared__ float den_s;
    const int g = blockIdx.x, tid = threadIdx.x;
    const int lane = tid & 63;

    for (int p = tid; p < NPG * H; p += 256) h_s[0][p] = h[g * NPG * H + p];
    if (tid < H) gf_s[tid] = gf[g * H + tid];
    __syncthreads();

    {
        const int n = tid >> 3, l = tid & 7;
        float p = 0.f;
        for (int jj = l; jj < H; jj += 8) {
            p = fmaf(h_s[n][jj], lgW[H + jj], p);
            p = fmaf(fmaxf(gf_s[jj], 0.f), lgW[jj], p);
        }
        p += __shfl_xor(p, 1);
        p += __shfl_xor(p, 2);
        p += __shfl_xor(p, 4);
        if (l == 0) {
            float z = p + lgb[0];
            z_s[n] = z > 0.f ? z : 0.01f * z;
        }
    }
    __syncthreads();

    if (tid < 64) {
        float z = (lane < NPG) ? z_s[lane] : -1e30f;
        float m = z;
        m = fmaxf(m, __shfl_xor(m, 1));
        m = fmaxf(m, __shfl_xor(m, 2));
        m = fmaxf(m, __shfl_xor(m, 4));
        m = fmaxf(m, __shfl_xor(m, 8));
        m = fmaxf(m, __shfl_xor(m, 16));
        float e = (lane < NPG) ? __expf(z - m) : 0.f;
        float d = e;
        d += __shfl_xor(d, 1);
        d += __shfl_xor(d, 2);
        d += __shfl_xor(d, 4);
        d += __shfl_xor(d, 8);
        d += __shfl_xor(d, 16);
        if (lane < NPG) a_s[lane] = e;
        if (lane == 0) den_s = d;
    }
    __syncthreads();

    if (tid < H) {
        float s = 0.f;
        for (int n = 0; n < NPG; n++) s = fmaf(a_s[n], h_s[n][tid], s);
        wh_out[g * H + tid] = s / den_s;
    }
}

// ---------------- fused ctx-projection + GRU: 8 graphs/block, 512 threads ----------------
#define GPB 8
#define GP 9
__global__ __launch_bounds__(512) void k_projgru(const float* __restrict__ wh,
                                                 const float* __restrict__ gf,
                                                 const float* __restrict__ prW,
                                                 const float* __restrict__ prb,
                                                 const float* __restrict__ Wih,
                                                 const float* __restrict__ Whh,
                                                 const float* __restrict__ bih,
                                                 const float* __restrict__ bhh,
                                                 float* __restrict__ gf_out) {
    __shared__ float wh_s[GPB][H];
    __shared__ float gfs[GPB][H];
    __shared__ float ctx_s[GPB][H];
    __shared__ float gi_s[3 * H][GP];
    __shared__ float gh_s[3 * H][GP];
    const int gbase = blockIdx.x * GPB, tid = threadIdx.x;

    for (int p = tid; p < GPB * H; p += 512) {
        wh_s[0][p] = wh[(size_t)gbase * H + p];
        gfs[0][p] = gf[(size_t)gbase * H + p];
    }
    __syncthreads();

    // ---- proj (R11 k_proj math, PGB=8): ctx = elu(wh @ prW + prb) ----
    {
        const int j = tid;
        if (j < H) {
            float acc[GPB];
#pragma unroll
            for (int q = 0; q < GPB; q++) acc[q] = 0.f;
            for (int i = 0; i < H; i++) {
                float w = prW[i * H + j];
#pragma unroll
                for (int q = 0; q < GPB; q++) acc[q] = fmaf(wh_s[q][i], w, acc[q]);
            }
            float bj = prb[j];
            for (int q = 0; q < GPB; q++) {
                float s = acc[q] + bj;
                ctx_s[q][j] = s > 0.f ? s : __expf(s) - 1.f;
            }
        }
    }
    __syncthreads();

    // ---- gru gates (R11 k_gru math) ----
    for (int k = tid; k < 3 * H; k += 512) {
        float ai[GPB], ah[GPB];
        float bi = bih[k], bh = bhh[k];
#pragma unroll
        for (int q = 0; q < GPB; q++) { ai[q] = bi; ah[q] = bh; }
        const float4* wi4 = (const float4*)(Wih + (size_t)k * H);
        const float4* wh4 = (const float4*)(Whh + (size_t)k * H);
        for (int j4 = 0; j4 < H / 4; j4++) {
            float4 wi = wi4[j4];
            float4 wg = wh4[j4];
            int jj = j4 * 4;
#pragma unroll
            for (int q = 0; q < GPB; q++) {
                ai[q] = fmaf(ctx_s[q][jj + 0], wi.x, ai[q]);
                ai[q] = fmaf(ctx_s[q][jj + 1], wi.y, ai[q]);
                ai[q] = fmaf(ctx_s[q][jj + 2], wi.z, ai[q]);
                ai[q] = fmaf(ctx_s[q][jj + 3], wi.w, ai[q]);
                ah[q] = fmaf(gfs[q][jj + 0], wg.x, ah[q]);
                ah[q] = fmaf(gfs[q][jj + 1], wg.y, ah[q]);
                ah[q] = fmaf(gfs[q][jj + 2], wg.z, ah[q]);
                ah[q] = fmaf(gfs[q][jj + 3], wg.w, ah[q]);
            }
        }
#pragma unroll
        for (int q = 0; q < GPB; q++) { gi_s[k][q] = ai[q]; gh_s[k][q] = ah[q]; }
    }
    __syncthreads();

    for (int p = tid; p < GPB * H; p += 512) {
        int q = p / H, jj = p - q * H;
        float r = sigmoidf_(gi_s[jj][q] + gh_s[jj][q]);
        float u = sigmoidf_(gi_s[H + jj][q] + gh_s[H + jj][q]);
        float nn = tanhf(gi_s[2 * H + jj][q] + r * gh_s[2 * H + jj][q]);
        gf_out[(gbase + q) * H + jj] = (1.f - u) * nn + u * gfs[q][jj];
    }
}

extern "C" void kernel_launch(void* const* d_in, const int* in_sizes, int n_in,
                              void* d_out, int out_size, void* d_ws, size_t ws_size,
                              hipStream_t stream) {
    const float* node_feat = (const float*)d_in[0];
    const float* edge_feat = (const float*)d_in[1];
    const int* src = (const int*)d_in[2];
    const float* node_W = (const float*)d_in[5];
    const float* node_b = (const float*)d_in[6];
    const float* edge_W = (const float*)d_in[7];
    const float* edge_b = (const float*)d_in[8];
    const float* gnn_W = (const float*)d_in[9];
    const float* gnn_b = (const float*)d_in[10];
    const float* lg_W = (const float*)d_in[11];
    const float* lg_b = (const float*)d_in[12];
    const float* pr_W = (const float*)d_in[13];
    const float* pr_b = (const float*)d_in[14];
    const float* W_ih = (const float*)d_in[15];
    const float* W_hh = (const float*)d_in[16];
    const float* b_ih = (const float*)d_in[17];
    const float* b_hh = (const float*)d_in[18];
    float* out = (float*)d_out;

    char* ws = (char*)d_ws;
    size_t off = 0;
    auto alloc = [&](size_t bytes) { void* p = ws + off; off += (bytes + 4095) & ~(size_t)4095; return p; };
    float* h = (float*)alloc((size_t)V * H * 4);
    unsigned short* Aedge = (unsigned short*)alloc((size_t)NE * EK * 2);
    unsigned short* WtHi = (unsigned short*)alloc((size_t)NL * NP * KP * 2);
    unsigned short* WtLo = (unsigned short*)alloc((size_t)NL * NP * KP * 2);
    unsigned short* eWp = (unsigned short*)alloc((size_t)NP * 64 * 2);
    float* gf_ws = (float*)alloc((size_t)G * H * 4);
    float* wh_ws = (float*)alloc((size_t)G * H * 4);

    {
        int wblocks = (SEG_W + SEG_EW + 255) / 256;
        k_prep<<<EFB + wblocks, 256, 0, stream>>>(edge_feat, gnn_W, edge_W, edge_b,
                                                  Aedge, WtHi, WtLo, eWp);
    }
    k_node_embed<<<V / 16, 256, 0, stream>>>(node_feat, node_W, node_b, h);

    k_mega<<<G, 256, 0, stream>>>(h, Aedge, eWp, src, WtHi, WtLo, gnn_b, gf_ws);

    for (int t = 0; t < 2; t++) {
        k_attn<<<G, 256, 0, stream>>>(h, gf_ws, lg_W + (size_t)t * 2 * H, lg_b + t, wh_ws);
        float* gout = (t == 1) ? out : gf_ws;
        k_projgru<<<G / GPB, 512, 0, stream>>>(wh_ws, gf_ws, pr_W + (size_t)t * H * H,
                                               pr_b + (size_t)t * H,
                                               W_ih + (size_t)t * 3 * H * H,
                                               W_hh + (size_t)t * 3 * H * H,
                                               b_ih + (size_t)t * 3 * H,
                                               b_hh + (size_t)t * 3 * H, gout);
    }
}